// Round 2
// baseline (537.776 us; speedup 1.0000x reference)
//
#include <hip/hip_runtime.h>
#include <hip/hip_bf16.h>

// ObjectRelationNetwork on MI355X — round 2.
// h[p=(i,j)] = relu(U'[i] + V[j]), U' = O@W1a^T + b1, V = O@W1b^T.
// Round-2 change: NO h-tile in LDS, NO barriers in the main loop.
// MFMA operands flipped: A = W2 (rows o), B = h built on-the-fly per lane from
// U/V LDS (32 KB total -> 3 WG/CU). D layout gives 4 consecutive o per lane
// -> float4 stores. Output e (252 MB fp32) write is the roofline (~40 us).

typedef __attribute__((ext_vector_type(8))) short bf16x8;   // 8 bf16 = 4 VGPRs
typedef __attribute__((ext_vector_type(4))) float f32x4;    // MFMA C/D

#define MFMA16(a, b, c) __builtin_amdgcn_mfma_f32_16x16x32_bf16((a), (b), (c), 0, 0, 0)

#define E_ELEMS 62914560ull   // 240*1024*256 (e), then 245760 all_is_obj floats

__device__ __forceinline__ short f2bf(float f) {          // RNE float->bf16
  unsigned u = __builtin_bit_cast(unsigned, f);
  u += 0x7fffu + ((u >> 16) & 1u);
  return (short)(u >> 16);
}
__device__ __forceinline__ float bf2f(short s) {
  unsigned u = ((unsigned)(unsigned short)s) << 16;
  return __builtin_bit_cast(float, u);
}

// ---- prep: W2 (256x256 fp32, W2[o][k]) -> bf16 A-fragment layout W2L[k>>3][o][k&7]
__global__ void prep_w2(const float* __restrict__ W2, short* __restrict__ W2L) {
  int t = blockIdx.x * 256 + threadIdx.x;   // t == kb*256 + o
  int kb = t >> 8;
  int o  = t & 255;
  const float* p = W2 + (size_t)o * 256 + kb * 8;
  float4 x = *(const float4*)p;
  float4 y = *(const float4*)(p + 4);
  bf16x8 f;
  f[0] = f2bf(x.x); f[1] = f2bf(x.y); f[2] = f2bf(x.z); f[3] = f2bf(x.w);
  f[4] = f2bf(y.x); f[5] = f2bf(y.y); f[6] = f2bf(y.z); f[7] = f2bf(y.w);
  *(bf16x8*)&W2L[(size_t)t * 8] = f;
}

// ---- main: 960 blocks (4 per (b,t)), 256 threads (4 waves), 32 KB LDS.
__global__ __launch_bounds__(256, 3) void orn_main(
    const float* __restrict__ objs, const float* __restrict__ W1,
    const float* __restrict__ b1, const float* __restrict__ b2,
    const short* __restrict__ W2L, float* __restrict__ out) {
  __shared__ short ULs[32 * 32 * 8];   // [kb=o>>3][i][o&7]  bf16 of U'=U+b1  (16 KB)
  __shared__ short VLs[32 * 32 * 8];   // [kb][j][jj]                         (16 KB)

  float* PS = (float*)ULs;             // phase-1 scratch (1 KB), dead before UL writes
  float* FC = PS + 256;                // 32 clip values

  const int tid = threadIdx.x;
  const int bid = blockIdx.x;
  const int bt  = bid >> 2;            // 0..239
  const int q   = bid & 3;             // row-quarter of this slab
  const int b   = bt / 15;
  const int tm  = bt - b * 15;         // t-1
  const float* O = objs + (size_t)(b * 16 + tm + 1) * (32 * 128);

  const int lane = tid & 63;
  const int w    = tid >> 6;           // wave 0..3
  const int l15  = lane & 15;
  const int quad = lane >> 4;
  const int n0   = w * 64;             // this wave's o-range base (o split 4x64)

  // ---------------- Phase 1: fp32 row sums -> all_is_obj (output 1) ----------------
  {
    int i = tid >> 3, c = tid & 7;
    const float* p = O + i * 128 + c * 16;
    float s = 0.f;
#pragma unroll
    for (int e = 0; e < 4; e++) {
      float4 v = *(const float4*)(p + e * 4);
      s += v.x + v.y + v.z + v.w;
    }
    PS[tid] = s;
  }
  __syncthreads();
  if (tid < 32) {
    float s = 0.f;
#pragma unroll
    for (int c = 0; c < 8; c++) s += PS[tid * 8 + c];
    FC[tid] = fminf(fmaxf(s, 0.f), 1.f);
  }
  __syncthreads();
  {
    int p = q * 256 + tid;             // this WG's 256 pairs
    int i = p >> 5, j = p & 31;
    float v = FC[i] * FC[j] * (float)(tm + 1);
    out[E_ELEMS + (size_t)bt * 1024 + p] = fminf(fmaxf(v, 0.f), 1.f);
  }

  // ---------------- Phase 2: U' and V (32x256) via MFMA (registers only) -----------
  f32x4 accU[2][4], accV[2][4];
  {
    bf16x8 afr[2][4];                  // O as A: A[m=i=ms*16+l15][k=ks*32+quad*8+jj]
#pragma unroll
    for (int ms = 0; ms < 2; ms++)
#pragma unroll
      for (int ks = 0; ks < 4; ks++) {
        const float* p = O + (ms * 16 + l15) * 128 + ks * 32 + quad * 8;
        float4 x = *(const float4*)p;
        float4 y = *(const float4*)(p + 4);
        bf16x8 f;
        f[0] = f2bf(x.x); f[1] = f2bf(x.y); f[2] = f2bf(x.z); f[3] = f2bf(x.w);
        f[4] = f2bf(y.x); f[5] = f2bf(y.y); f[6] = f2bf(y.z); f[7] = f2bf(y.w);
        afr[ms][ks] = f;
      }
    const f32x4 zf = {0.f, 0.f, 0.f, 0.f};
#pragma unroll
    for (int ms = 0; ms < 2; ms++)
#pragma unroll
      for (int ns = 0; ns < 4; ns++) { accU[ms][ns] = zf; accV[ms][ns] = zf; }
#pragma unroll
    for (int ks = 0; ks < 4; ks++) {
#pragma unroll
      for (int ns = 0; ns < 4; ns++) {
        // B[k=d][n=o] = W1[o][d] (U) / W1[o][128+d] (V)
        const float* pu = W1 + (size_t)(n0 + ns * 16 + l15) * 256 + ks * 32 + quad * 8;
        float4 xu = *(const float4*)pu;
        float4 yu = *(const float4*)(pu + 4);
        float4 xv = *(const float4*)(pu + 128);
        float4 yv = *(const float4*)(pu + 132);
        bf16x8 bu, bv;
        bu[0] = f2bf(xu.x); bu[1] = f2bf(xu.y); bu[2] = f2bf(xu.z); bu[3] = f2bf(xu.w);
        bu[4] = f2bf(yu.x); bu[5] = f2bf(yu.y); bu[6] = f2bf(yu.z); bu[7] = f2bf(yu.w);
        bv[0] = f2bf(xv.x); bv[1] = f2bf(xv.y); bv[2] = f2bf(xv.z); bv[3] = f2bf(xv.w);
        bv[4] = f2bf(yv.x); bv[5] = f2bf(yv.y); bv[6] = f2bf(yv.z); bv[7] = f2bf(yv.w);
#pragma unroll
        for (int ms = 0; ms < 2; ms++) {
          accU[ms][ns] = MFMA16(afr[ms][ks], bu, accU[ms][ns]);
          accV[ms][ns] = MFMA16(afr[ms][ks], bv, accV[ms][ns]);
        }
      }
    }
  }
  __syncthreads();                     // FC consumers done -> safe to overwrite ULs

  // D: col=l15 -> o, row=quad*4+r -> i. Fold b1 into U'. Write bf16 frag layout.
#pragma unroll
  for (int ms = 0; ms < 2; ms++)
#pragma unroll
    for (int ns = 0; ns < 4; ns++) {
      int o  = n0 + ns * 16 + l15;
      float bb = b1[o];
      int kb = o >> 3, jj = o & 7;
#pragma unroll
      for (int r = 0; r < 4; r++) {
        int i = ms * 16 + quad * 4 + r;
        ULs[(kb * 32 + i) * 8 + jj] = f2bf(accU[ms][ns][r] + bb);
        VLs[(kb * 32 + i) * 8 + jj] = f2bf(accV[ms][ns][r]);
      }
    }
  __syncthreads();                     // fragments ready — LAST barrier

  // ---------------- Main GEMM: e = relu(h @ W2^T + b2), barrier-free --------------
  float4 b2v[4];                       // b2[o] for o = n0+ms*16+quad*4+r  (r matches)
#pragma unroll
  for (int ms = 0; ms < 4; ms++)
    b2v[ms] = *(const float4*)&b2[n0 + ms * 16 + quad * 4];

  const int R0 = q * 256;              // WG's pair base within slab
  const f32x4 zf = {0.f, 0.f, 0.f, 0.f};

#pragma unroll 1
  for (int c = 0; c < 4; c++) {        // 4 chunks of 64 pairs; no barriers
    f32x4 acc[4][4];                   // [ms: o-16tile][ns: p-16tile]
#pragma unroll
    for (int ms = 0; ms < 4; ms++)
#pragma unroll
      for (int ns = 0; ns < 4; ns++) acc[ms][ns] = zf;

#pragma unroll
    for (int ks = 0; ks < 8; ks++) {
      const int kb = ks * 4 + quad;
      bf16x8 aw[4];                    // W2 as A: A[m=o-off=l15][k=quad*8+jj]
#pragma unroll
      for (int ms = 0; ms < 4; ms++)
        aw[ms] = *(const bf16x8*)&W2L[((size_t)kb * 256 + n0 + ms * 16 + l15) * 8];
#pragma unroll
      for (int ns = 0; ns < 4; ns++) {
        // B[k=quad*8+jj][n=p-off=l15]: h row p = R0 + c*64 + ns*16 + l15
        int pl = ns * 16 + l15;        // 0..63 within chunk
        int i  = 8 * q + 2 * c + (pl >> 5);
        int j  = pl & 31;
        bf16x8 u = *(bf16x8*)&ULs[(kb * 32 + i) * 8];
        bf16x8 v = *(bf16x8*)&VLs[(kb * 32 + j) * 8];
        bf16x8 hh;
#pragma unroll
        for (int e = 0; e < 8; e++)
          hh[e] = f2bf(fmaxf(bf2f(u[e]) + bf2f(v[e]), 0.f));
#pragma unroll
        for (int ms = 0; ms < 4; ms++)
          acc[ms][ns] = MFMA16(aw[ms], hh, acc[ms][ns]);
      }
    }

    // epilogue: lane holds e[p = ..+ns*16+l15][o = n0+ms*16+quad*4 + r], r=0..3
    size_t rowbase = (size_t)bt * 1024 + R0 + c * 64;
#pragma unroll
    for (int ms = 0; ms < 4; ms++)
#pragma unroll
      for (int ns = 0; ns < 4; ns++) {
        float4 vs;
        vs.x = fmaxf(acc[ms][ns][0] + b2v[ms].x, 0.f);
        vs.y = fmaxf(acc[ms][ns][1] + b2v[ms].y, 0.f);
        vs.z = fmaxf(acc[ms][ns][2] + b2v[ms].z, 0.f);
        vs.w = fmaxf(acc[ms][ns][3] + b2v[ms].w, 0.f);
        size_t row = rowbase + ns * 16 + l15;
        *(float4*)&out[row * 256 + n0 + ms * 16 + quad * 4] = vs;
      }
  }
}

extern "C" void kernel_launch(void* const* d_in, const int* in_sizes, int n_in,
                              void* d_out, int out_size, void* d_ws, size_t ws_size,
                              hipStream_t stream) {
  const float* objs = (const float*)d_in[0];
  const float* W1   = (const float*)d_in[1];
  const float* b1   = (const float*)d_in[2];
  const float* W2   = (const float*)d_in[3];
  const float* b2   = (const float*)d_in[4];
  float* out = (float*)d_out;
  short* W2L = (short*)d_ws;           // 128 KB bf16 A-fragment-layout W2

  prep_w2<<<32, 256, 0, stream>>>(W2, W2L);
  orn_main<<<960, 256, 0, stream>>>(objs, W1, b1, b2, W2L, out);
}

// Round 4
// 386.788 us; speedup vs baseline: 1.3904x; 1.3904x over previous
//
#include <hip/hip_runtime.h>
#include <hip/hip_bf16.h>

// ObjectRelationNetwork on MI355X — round 4 (round 3 + compile fix).
// h[p=(i,j)] = relu(U'[i] + V[j]), U' = O@W1a^T + b1, V = O@W1b^T.
// vs round 2 (latency-bound re-fetching W2 480 MB from HBM: FETCH=491MB,
// MfmaUtil 4%):
//  - W2 fragments preloaded into 128 VGPRs per wave (one-time, L2-hot read).
//    Inner loop touches ONLY LDS + MFMA + stores. No global reads.
//  - Epilogue stores reordered ns-outer/ms-inner so both 64B halves of each
//    128B line are adjacent instructions (fixes WRITE=2x inflation).
//  - Nontemporal f32x4 (ext_vector) stores: 253 MB stream skips L2 thrash.
//  - Cheap packed h-build (~11 VALU per 2 elems, round-half-up).

typedef __attribute__((ext_vector_type(8))) short bf16x8;   // 8 bf16 = 4 VGPRs
typedef __attribute__((ext_vector_type(4))) float f32x4;    // MFMA C/D / stores

#define MFMA16(a, b, c) __builtin_amdgcn_mfma_f32_16x16x32_bf16((a), (b), (c), 0, 0, 0)

#define E_ELEMS 62914560ull   // 240*1024*256 (e), then 245760 all_is_obj floats

__device__ __forceinline__ short f2bf(float f) {          // RNE float->bf16
  unsigned u = __builtin_bit_cast(unsigned, f);
  u += 0x7fffu + ((u >> 16) & 1u);
  return (short)(u >> 16);
}

// relu(u+v) for a packed pair of bf16 (one dword each), round-half-up pack.
__device__ __forceinline__ unsigned hpair(unsigned ud, unsigned vd) {
  float ulo = __builtin_bit_cast(float, ud << 16);
  float uhi = __builtin_bit_cast(float, ud & 0xffff0000u);
  float vlo = __builtin_bit_cast(float, vd << 16);
  float vhi = __builtin_bit_cast(float, vd & 0xffff0000u);
  float slo = fmaxf(ulo + vlo, 0.f);
  float shi = fmaxf(uhi + vhi, 0.f);
  unsigned rlo = __builtin_bit_cast(unsigned, slo) + 0x8000u;
  unsigned rhi = __builtin_bit_cast(unsigned, shi) + 0x8000u;
  return (rhi & 0xffff0000u) | (rlo >> 16);
}

// ---- prep: W2 (256x256 fp32, W2[o][k]) -> bf16 A-fragment layout W2L[k>>3][o][k&7]
__global__ void prep_w2(const float* __restrict__ W2, short* __restrict__ W2L) {
  int t = blockIdx.x * 256 + threadIdx.x;   // t == kb*256 + o
  int kb = t >> 8;
  int o  = t & 255;
  const float* p = W2 + (size_t)o * 256 + kb * 8;
  float4 x = *(const float4*)p;
  float4 y = *(const float4*)(p + 4);
  bf16x8 f;
  f[0] = f2bf(x.x); f[1] = f2bf(x.y); f[2] = f2bf(x.z); f[3] = f2bf(x.w);
  f[4] = f2bf(y.x); f[5] = f2bf(y.y); f[6] = f2bf(y.z); f[7] = f2bf(y.w);
  *(bf16x8*)&W2L[(size_t)t * 8] = f;
}

// ---- main: 960 blocks (4 per (b,t)), 256 threads (4 waves), 32 KB LDS, 2 WG/CU.
__global__ __launch_bounds__(256, 2) void orn_main(
    const float* __restrict__ objs, const float* __restrict__ W1,
    const float* __restrict__ b1, const float* __restrict__ b2,
    const short* __restrict__ W2L, float* __restrict__ out) {
  __shared__ short ULs[32 * 32 * 8];   // [kb=o>>3][i][o&7]  bf16 of U'=U+b1  (16 KB)
  __shared__ short VLs[32 * 32 * 8];   // [kb][j][jj]                         (16 KB)

  float* PS = (float*)ULs;             // phase-1 scratch (1 KB), dead before UL writes
  float* FC = PS + 256;                // 32 clip values

  const int tid = threadIdx.x;
  const int bid = blockIdx.x;
  const int bt  = bid >> 2;            // 0..239
  const int q   = bid & 3;             // row-quarter of this slab
  const int b   = bt / 15;
  const int tm  = bt - b * 15;         // t-1
  const float* O = objs + (size_t)(b * 16 + tm + 1) * (32 * 128);

  const int lane = tid & 63;
  const int w    = tid >> 6;           // wave 0..3
  const int l15  = lane & 15;
  const int quad = lane >> 4;
  const int n0   = w * 64;             // this wave's o-range base (o split 4x64)

  // ---------------- Phase 1: fp32 row sums -> all_is_obj (output 1) ----------------
  {
    int i = tid >> 3, c = tid & 7;
    const float* p = O + i * 128 + c * 16;
    float s = 0.f;
#pragma unroll
    for (int e = 0; e < 4; e++) {
      float4 v = *(const float4*)(p + e * 4);
      s += v.x + v.y + v.z + v.w;
    }
    PS[tid] = s;
  }
  __syncthreads();
  if (tid < 32) {
    float s = 0.f;
#pragma unroll
    for (int c = 0; c < 8; c++) s += PS[tid * 8 + c];
    FC[tid] = fminf(fmaxf(s, 0.f), 1.f);
  }
  __syncthreads();
  {
    int p = q * 256 + tid;             // this WG's 256 pairs
    int i = p >> 5, j = p & 31;
    float v = FC[i] * FC[j] * (float)(tm + 1);
    out[E_ELEMS + (size_t)bt * 1024 + p] = fminf(fmaxf(v, 0.f), 1.f);
  }

  // ---------------- Phase 2: U' and V (32x256) via MFMA (registers only) -----------
  f32x4 accU[2][4], accV[2][4];
  {
    bf16x8 afr[2][4];                  // O as A: A[m=i=ms*16+l15][k=ks*32+quad*8+jj]
#pragma unroll
    for (int ms = 0; ms < 2; ms++)
#pragma unroll
      for (int ks = 0; ks < 4; ks++) {
        const float* p = O + (ms * 16 + l15) * 128 + ks * 32 + quad * 8;
        float4 x = *(const float4*)p;
        float4 y = *(const float4*)(p + 4);
        bf16x8 f;
        f[0] = f2bf(x.x); f[1] = f2bf(x.y); f[2] = f2bf(x.z); f[3] = f2bf(x.w);
        f[4] = f2bf(y.x); f[5] = f2bf(y.y); f[6] = f2bf(y.z); f[7] = f2bf(y.w);
        afr[ms][ks] = f;
      }
    const f32x4 zf = {0.f, 0.f, 0.f, 0.f};
#pragma unroll
    for (int ms = 0; ms < 2; ms++)
#pragma unroll
      for (int ns = 0; ns < 4; ns++) { accU[ms][ns] = zf; accV[ms][ns] = zf; }
#pragma unroll
    for (int ks = 0; ks < 4; ks++) {
#pragma unroll
      for (int ns = 0; ns < 4; ns++) {
        // B[k=d][n=o] = W1[o][d] (U) / W1[o][128+d] (V)
        const float* pu = W1 + (size_t)(n0 + ns * 16 + l15) * 256 + ks * 32 + quad * 8;
        float4 xu = *(const float4*)pu;
        float4 yu = *(const float4*)(pu + 4);
        float4 xv = *(const float4*)(pu + 128);
        float4 yv = *(const float4*)(pu + 132);
        bf16x8 bu, bv;
        bu[0] = f2bf(xu.x); bu[1] = f2bf(xu.y); bu[2] = f2bf(xu.z); bu[3] = f2bf(xu.w);
        bu[4] = f2bf(yu.x); bu[5] = f2bf(yu.y); bu[6] = f2bf(yu.z); bu[7] = f2bf(yu.w);
        bv[0] = f2bf(xv.x); bv[1] = f2bf(xv.y); bv[2] = f2bf(xv.z); bv[3] = f2bf(xv.w);
        bv[4] = f2bf(yv.x); bv[5] = f2bf(yv.y); bv[6] = f2bf(yv.z); bv[7] = f2bf(yv.w);
#pragma unroll
        for (int ms = 0; ms < 2; ms++) {
          accU[ms][ns] = MFMA16(afr[ms][ks], bu, accU[ms][ns]);
          accV[ms][ns] = MFMA16(afr[ms][ks], bv, accV[ms][ns]);
        }
      }
    }
  }
  __syncthreads();                     // FC consumers done -> safe to overwrite ULs

  // D: col=l15 -> o, row=quad*4+r -> i. Fold b1 into U'. Write bf16 frag layout.
#pragma unroll
  for (int ms = 0; ms < 2; ms++)
#pragma unroll
    for (int ns = 0; ns < 4; ns++) {
      int o  = n0 + ns * 16 + l15;
      float bb = b1[o];
      int kb = o >> 3, jj = o & 7;
#pragma unroll
      for (int r = 0; r < 4; r++) {
        int i = ms * 16 + quad * 4 + r;
        ULs[(kb * 32 + i) * 8 + jj] = f2bf(accU[ms][ns][r] + bb);
        VLs[(kb * 32 + i) * 8 + jj] = f2bf(accV[ms][ns][r]);
      }
    }
  __syncthreads();                     // fragments ready — LAST barrier

  // ------- Preload W2 A-fragments into registers (accU/accV now dead) -------
  // aw[ms][ks]: A[m = n0+ms*16+l15][k = (ks*4+quad)*8 + jj]  — 128 VGPRs.
  bf16x8 aw[4][8];
#pragma unroll
  for (int ms = 0; ms < 4; ms++)
#pragma unroll
    for (int ks = 0; ks < 8; ks++)
      aw[ms][ks] = *(const bf16x8*)
          &W2L[((size_t)(ks * 4 + quad) * 256 + n0 + ms * 16 + l15) * 8];

  f32x4 b2v[4];                        // b2[o] for o = n0+ms*16+quad*4+r
#pragma unroll
  for (int ms = 0; ms < 4; ms++)
    b2v[ms] = *(const f32x4*)&b2[n0 + ms * 16 + quad * 4];

  const int R0 = q * 256;              // WG's pair base within slab
  const f32x4 zf = {0.f, 0.f, 0.f, 0.f};

#pragma unroll 1
  for (int c = 0; c < 4; c++) {        // 4 chunks of 64 pairs; no barriers
    f32x4 acc[4][4];                   // [ms: o-16tile][ns: p-16tile]
#pragma unroll
    for (int ms = 0; ms < 4; ms++)
#pragma unroll
      for (int ns = 0; ns < 4; ns++) acc[ms][ns] = zf;

#pragma unroll
    for (int ks = 0; ks < 8; ks++) {
      const int kb = ks * 4 + quad;
#pragma unroll
      for (int ns = 0; ns < 4; ns++) {
        // B[k=quad*8+jj][n=p-off=l15]: h row p = R0 + c*64 + ns*16 + l15
        int pl = ns * 16 + l15;        // 0..63 within chunk
        int i  = 8 * q + 2 * c + (pl >> 5);
        int j  = pl & 31;
        uint4 ud = *(const uint4*)&ULs[(kb * 32 + i) * 8];  // broadcast within quad
        uint4 vd = *(const uint4*)&VLs[(kb * 32 + j) * 8];  // 256B contiguous/quad
        uint4 hd;
        hd.x = hpair(ud.x, vd.x);
        hd.y = hpair(ud.y, vd.y);
        hd.z = hpair(ud.z, vd.z);
        hd.w = hpair(ud.w, vd.w);
        bf16x8 hh = __builtin_bit_cast(bf16x8, hd);
#pragma unroll
        for (int ms = 0; ms < 4; ms++)
          acc[ms][ns] = MFMA16(aw[ms][ks], hh, acc[ms][ns]);
      }
    }

    // epilogue: lane holds e[p = ..+ns*16+l15][o = n0+ms*16+quad*4 + r], r=0..3
    // ns OUTER so the 4 ms-stores (4 x 64B spanning 2 lines) are back-to-back.
    size_t rowbase = (size_t)bt * 1024 + R0 + c * 64;
#pragma unroll
    for (int ns = 0; ns < 4; ns++) {
      size_t row = rowbase + ns * 16 + l15;
      float* rp = &out[row * 256 + n0 + quad * 4];
#pragma unroll
      for (int ms = 0; ms < 4; ms++) {
        f32x4 vs;
        vs.x = fmaxf(acc[ms][ns][0] + b2v[ms].x, 0.f);
        vs.y = fmaxf(acc[ms][ns][1] + b2v[ms].y, 0.f);
        vs.z = fmaxf(acc[ms][ns][2] + b2v[ms].z, 0.f);
        vs.w = fmaxf(acc[ms][ns][3] + b2v[ms].w, 0.f);
        __builtin_nontemporal_store(vs, (f32x4*)(rp + ms * 16));
      }
    }
  }
}

extern "C" void kernel_launch(void* const* d_in, const int* in_sizes, int n_in,
                              void* d_out, int out_size, void* d_ws, size_t ws_size,
                              hipStream_t stream) {
  const float* objs = (const float*)d_in[0];
  const float* W1   = (const float*)d_in[1];
  const float* b1   = (const float*)d_in[2];
  const float* W2   = (const float*)d_in[3];
  const float* b2   = (const float*)d_in[4];
  float* out = (float*)d_out;
  short* W2L = (short*)d_ws;           // 128 KB bf16 A-fragment-layout W2

  prep_w2<<<32, 256, 0, stream>>>(W2, W2L);
  orn_main<<<960, 256, 0, stream>>>(objs, W1, b1, b2, W2L, out);
}

// Round 5
// 371.513 us; speedup vs baseline: 1.4475x; 1.0411x over previous
//
#include <hip/hip_runtime.h>
#include <hip/hip_bf16.h>

// ObjectRelationNetwork on MI355X — round 5.
// h[p=(i,j)] = relu(U'[i] + V[j]), U' = O@W1a^T + b1, V = O@W1b^T.
// Round-5 change vs round 4 (compiler sank the W2 VGPR preload back to
// per-chunk global loads -> FETCH 229MB, latency-bound, MfmaUtil 7.8%):
//  - WGs partitioned by o-QUARTER (not p-quarter): all 4 waves share one
//    64-wide o range, so the WG's W2 slice (32 KB bf16) lives in LDS.
//    Inner loop is structurally LDS+VALU+MFMA only — nothing to sink.
//  - LDS = UL 16K + VL 16K + AW 32K = exactly 64 KB -> 2 WG/CU.
//  - Plain (non-NT) stores, ns-outer/ms-inner: test 64B-half line merging.

typedef __attribute__((ext_vector_type(8))) short bf16x8;   // 8 bf16 = 4 VGPRs
typedef __attribute__((ext_vector_type(4))) float f32x4;    // MFMA C/D / stores

#define MFMA16(a, b, c) __builtin_amdgcn_mfma_f32_16x16x32_bf16((a), (b), (c), 0, 0, 0)

#define E_ELEMS 62914560ull   // 240*1024*256 (e), then 245760 all_is_obj floats

__device__ __forceinline__ short f2bf(float f) {          // RNE float->bf16
  unsigned u = __builtin_bit_cast(unsigned, f);
  u += 0x7fffu + ((u >> 16) & 1u);
  return (short)(u >> 16);
}

// relu(u+v) for a packed pair of bf16 (one dword each), round-half-up pack.
__device__ __forceinline__ unsigned hpair(unsigned ud, unsigned vd) {
  float ulo = __builtin_bit_cast(float, ud << 16);
  float uhi = __builtin_bit_cast(float, ud & 0xffff0000u);
  float vlo = __builtin_bit_cast(float, vd << 16);
  float vhi = __builtin_bit_cast(float, vd & 0xffff0000u);
  float slo = fmaxf(ulo + vlo, 0.f);
  float shi = fmaxf(uhi + vhi, 0.f);
  unsigned rlo = __builtin_bit_cast(unsigned, slo) + 0x8000u;
  unsigned rhi = __builtin_bit_cast(unsigned, shi) + 0x8000u;
  return (rhi & 0xffff0000u) | (rlo >> 16);
}

// ---- prep: W2 (256x256 fp32, W2[o][k]) -> bf16 A-frag layout, per-o-quarter
// contiguous: W2L[q][kb][m=o&63][jj] where o = q*64+m, k = kb*8+jj.
__global__ void prep_w2(const float* __restrict__ W2, short* __restrict__ W2L) {
  int t = blockIdx.x * 256 + threadIdx.x;   // t == kb*256 + o
  int kb = t >> 8;
  int o  = t & 255;
  const float* p = W2 + (size_t)o * 256 + kb * 8;
  float4 x = *(const float4*)p;
  float4 y = *(const float4*)(p + 4);
  bf16x8 f;
  f[0] = f2bf(x.x); f[1] = f2bf(x.y); f[2] = f2bf(x.z); f[3] = f2bf(x.w);
  f[4] = f2bf(y.x); f[5] = f2bf(y.y); f[6] = f2bf(y.z); f[7] = f2bf(y.w);
  int idx = ((o >> 6) * 32 + kb) * 64 + (o & 63);
  *(bf16x8*)&W2L[(size_t)idx * 8] = f;
}

// ---- main: 960 blocks = 240 slabs x 4 o-quarters, 256 threads, 64 KB LDS.
__global__ __launch_bounds__(256, 2) void orn_main(
    const float* __restrict__ objs, const float* __restrict__ W1,
    const float* __restrict__ b1, const float* __restrict__ b2,
    const short* __restrict__ W2L, float* __restrict__ out) {
  __shared__ short ULs[32 * 32 * 8];   // [kb=o'>>3][i][o'&7] bf16 of U'=U+b1 (16 KB)
  __shared__ short VLs[32 * 32 * 8];   // [kb][j][jj]                         (16 KB)
  __shared__ short AW[32 * 64 * 8];    // [kb][m=o-64q][jj]  W2 A-frags       (32 KB)

  float* PS = (float*)ULs;             // phase-1 scratch (1 KB), dead before UL writes
  float* FC = PS + 256;                // 32 clip values

  const int tid = threadIdx.x;
  const int bid = blockIdx.x;
  const int bt  = bid >> 2;            // 0..239
  const int q   = bid & 3;             // o-QUARTER of this slab
  const int b   = bt / 15;
  const int tm  = bt - b * 15;         // t-1
  const float* O = objs + (size_t)(b * 16 + tm + 1) * (32 * 128);

  const int lane = tid & 63;
  const int w    = tid >> 6;           // wave 0..3
  const int l15  = lane & 15;
  const int quad = lane >> 4;
  const int n0   = w * 64;             // wave's o'-slice for phase-2 U/V compute

  // ---- AW copy-in: issue early, overlaps phases 1-2; final barrier covers it.
  {
    const short* W2q = W2L + (size_t)q * (2048 * 8);
#pragma unroll
    for (int it = 0; it < 8; it++) {
      int idx = it * 256 + tid;
      *(bf16x8*)&AW[(size_t)idx * 8] = *(const bf16x8*)&W2q[(size_t)idx * 8];
    }
  }

  // ---------------- Phase 1: fp32 row sums -> all_is_obj (output 1) ----------------
  {
    int i = tid >> 3, c = tid & 7;
    const float* p = O + i * 128 + c * 16;
    float s = 0.f;
#pragma unroll
    for (int e = 0; e < 4; e++) {
      float4 v = *(const float4*)(p + e * 4);
      s += v.x + v.y + v.z + v.w;
    }
    PS[tid] = s;
  }
  __syncthreads();
  if (tid < 32) {
    float s = 0.f;
#pragma unroll
    for (int c = 0; c < 8; c++) s += PS[tid * 8 + c];
    FC[tid] = fminf(fmaxf(s, 0.f), 1.f);
  }
  __syncthreads();
  {
    int p = q * 256 + tid;             // 4 WGs per slab each cover 256 pairs
    int i = p >> 5, j = p & 31;
    float v = FC[i] * FC[j] * (float)(tm + 1);
    out[E_ELEMS + (size_t)bt * 1024 + p] = fminf(fmaxf(v, 0.f), 1.f);
  }

  // ---------------- Phase 2: U' and V (32x256) via MFMA (registers only) -----------
  f32x4 accU[2][4], accV[2][4];
  {
    bf16x8 afr[2][4];                  // O as A: A[m=i=ms*16+l15][k=ks*32+quad*8+jj]
#pragma unroll
    for (int ms = 0; ms < 2; ms++)
#pragma unroll
      for (int ks = 0; ks < 4; ks++) {
        const float* p = O + (ms * 16 + l15) * 128 + ks * 32 + quad * 8;
        float4 x = *(const float4*)p;
        float4 y = *(const float4*)(p + 4);
        bf16x8 f;
        f[0] = f2bf(x.x); f[1] = f2bf(x.y); f[2] = f2bf(x.z); f[3] = f2bf(x.w);
        f[4] = f2bf(y.x); f[5] = f2bf(y.y); f[6] = f2bf(y.z); f[7] = f2bf(y.w);
        afr[ms][ks] = f;
      }
    const f32x4 zf = {0.f, 0.f, 0.f, 0.f};
#pragma unroll
    for (int ms = 0; ms < 2; ms++)
#pragma unroll
      for (int ns = 0; ns < 4; ns++) { accU[ms][ns] = zf; accV[ms][ns] = zf; }
#pragma unroll
    for (int ks = 0; ks < 4; ks++) {
#pragma unroll
      for (int ns = 0; ns < 4; ns++) {
        // B[k=d][n=o'] = W1[o'][d] (U) / W1[o'][128+d] (V)
        const float* pu = W1 + (size_t)(n0 + ns * 16 + l15) * 256 + ks * 32 + quad * 8;
        float4 xu = *(const float4*)pu;
        float4 yu = *(const float4*)(pu + 4);
        float4 xv = *(const float4*)(pu + 128);
        float4 yv = *(const float4*)(pu + 132);
        bf16x8 bu, bv;
        bu[0] = f2bf(xu.x); bu[1] = f2bf(xu.y); bu[2] = f2bf(xu.z); bu[3] = f2bf(xu.w);
        bu[4] = f2bf(yu.x); bu[5] = f2bf(yu.y); bu[6] = f2bf(yu.z); bu[7] = f2bf(yu.w);
        bv[0] = f2bf(xv.x); bv[1] = f2bf(xv.y); bv[2] = f2bf(xv.z); bv[3] = f2bf(xv.w);
        bv[4] = f2bf(yv.x); bv[5] = f2bf(yv.y); bv[6] = f2bf(yv.z); bv[7] = f2bf(yv.w);
#pragma unroll
        for (int ms = 0; ms < 2; ms++) {
          accU[ms][ns] = MFMA16(afr[ms][ks], bu, accU[ms][ns]);
          accV[ms][ns] = MFMA16(afr[ms][ks], bv, accV[ms][ns]);
        }
      }
    }
  }
  __syncthreads();                     // FC consumers done -> safe to overwrite ULs

  // D: col=l15 -> o', row=quad*4+r -> i. Fold b1 into U'. Write bf16 frag layout.
#pragma unroll
  for (int ms = 0; ms < 2; ms++)
#pragma unroll
    for (int ns = 0; ns < 4; ns++) {
      int o  = n0 + ns * 16 + l15;
      float bb = b1[o];
      int kb = o >> 3, jj = o & 7;
#pragma unroll
      for (int r = 0; r < 4; r++) {
        int i = ms * 16 + quad * 4 + r;
        ULs[(kb * 32 + i) * 8 + jj] = f2bf(accU[ms][ns][r] + bb);
        VLs[(kb * 32 + i) * 8 + jj] = f2bf(accV[ms][ns][r]);
      }
    }
  __syncthreads();                     // UL/VL/AW all ready — LAST barrier

  // ---------------- Main GEMM: e = relu(h @ W2^T + b2), barrier-free --------------
  f32x4 b2v[4];                        // b2[o] for o = 64q + ms*16 + quad*4 + r
#pragma unroll
  for (int ms = 0; ms < 4; ms++)
    b2v[ms] = *(const f32x4*)&b2[q * 64 + ms * 16 + quad * 4];

  const int PB = w * 256;              // wave's pair base within slab
  const f32x4 zf = {0.f, 0.f, 0.f, 0.f};

#pragma unroll 1
  for (int c = 0; c < 4; c++) {        // 4 chunks of 64 pairs; no barriers
    f32x4 acc[4][4];                   // [ms: o-16tile][ns: p-16tile]
#pragma unroll
    for (int ms = 0; ms < 4; ms++)
#pragma unroll
      for (int ns = 0; ns < 4; ns++) acc[ms][ns] = zf;

#pragma unroll
    for (int ks = 0; ks < 8; ks++) {
      const int kb = ks * 4 + quad;
      bf16x8 aw4[4];                   // W2 A-frags from LDS (WG-shared)
#pragma unroll
      for (int ms = 0; ms < 4; ms++)
        aw4[ms] = *(const bf16x8*)&AW[(kb * 64 + ms * 16 + l15) * 8];
#pragma unroll
      for (int ns = 0; ns < 4; ns++) {
        // B[k=quad*8+jj][n=p]: h row p = PB + c*64 + ns*16 + l15
        int pl = ns * 16 + l15;        // 0..63 within chunk
        int i  = 8 * w + 2 * c + (pl >> 5);
        int j  = pl & 31;
        uint4 ud = *(const uint4*)&ULs[(kb * 32 + i) * 8];  // broadcast in quad
        uint4 vd = *(const uint4*)&VLs[(kb * 32 + j) * 8];  // 256B contiguous
        uint4 hd;
        hd.x = hpair(ud.x, vd.x);
        hd.y = hpair(ud.y, vd.y);
        hd.z = hpair(ud.z, vd.z);
        hd.w = hpair(ud.w, vd.w);
        bf16x8 hh = __builtin_bit_cast(bf16x8, hd);
#pragma unroll
        for (int ms = 0; ms < 4; ms++)
          acc[ms][ns] = MFMA16(aw4[ms], hh, acc[ms][ns]);
      }
    }

    // epilogue: lane holds e[p = PB+c*64+ns*16+l15][o = 64q+ms*16+quad*4+r].
    // ns OUTER so ms-stores (64B halves of 128B lines) are adjacent.
    size_t rowbase = (size_t)bt * 1024 + PB + c * 64;
#pragma unroll
    for (int ns = 0; ns < 4; ns++) {
      size_t row = rowbase + ns * 16 + l15;
      float* rp = &out[row * 256 + q * 64 + quad * 4];
#pragma unroll
      for (int ms = 0; ms < 4; ms++) {
        f32x4 vs;
        vs.x = fmaxf(acc[ms][ns][0] + b2v[ms].x, 0.f);
        vs.y = fmaxf(acc[ms][ns][1] + b2v[ms].y, 0.f);
        vs.z = fmaxf(acc[ms][ns][2] + b2v[ms].z, 0.f);
        vs.w = fmaxf(acc[ms][ns][3] + b2v[ms].w, 0.f);
        *(f32x4*)(rp + ms * 16) = vs;
      }
    }
  }
}

extern "C" void kernel_launch(void* const* d_in, const int* in_sizes, int n_in,
                              void* d_out, int out_size, void* d_ws, size_t ws_size,
                              hipStream_t stream) {
  const float* objs = (const float*)d_in[0];
  const float* W1   = (const float*)d_in[1];
  const float* b1   = (const float*)d_in[2];
  const float* W2   = (const float*)d_in[3];
  const float* b2   = (const float*)d_in[4];
  float* out = (float*)d_out;
  short* W2L = (short*)d_ws;           // 128 KB bf16 per-quarter A-frag W2

  prep_w2<<<32, 256, 0, stream>>>(W2, W2L);
  orn_main<<<960, 256, 0, stream>>>(objs, W1, b1, b2, W2L, out);
}

// Round 6
// 358.063 us; speedup vs baseline: 1.5019x; 1.0376x over previous
//
#include <hip/hip_runtime.h>
#include <hip/hip_bf16.h>

// ObjectRelationNetwork on MI355X — round 6.
// h[p=(i,j)] = relu(U'[i] + V[j]), U' = O@W1a^T + b1, V = O@W1b^T.
// Round-6 change vs round 5 (FETCH stuck at 233 MB = per-WG full-W1 reads
// evicted from L2 by the store stream; 960 x 256 KB = 245 MB logical):
//  - orn_prep (240 WGs, one per slab): computes U'/V via MFMA while W1 is
//    L2-hot (all WGs co-resident), stores them bf16 in the exact LDS
//    fragment image in ws (7.9 MB), plus writes all_is_obj. Also folds the
//    W2->bf16 fragment prep (blocks 0..31).
//  - orn_main: 64 KB linear copy-in (W2 slice + U/V images) -> 1 barrier ->
//    pure LDS+MFMA GEMM -> plain ns-outer/ms-inner f32x4 stores.
//  - bid swizzle: 4 WGs of one slab differ by 8 -> same XCD -> UV L2-local.

typedef __attribute__((ext_vector_type(8))) short bf16x8;   // 8 bf16 = 4 VGPRs
typedef __attribute__((ext_vector_type(4))) float f32x4;    // MFMA C/D / stores

#define MFMA16(a, b, c) __builtin_amdgcn_mfma_f32_16x16x32_bf16((a), (b), (c), 0, 0, 0)

#define E_ELEMS 62914560ull   // 240*1024*256 (e), then 245760 all_is_obj floats

__device__ __forceinline__ short f2bf(float f) {          // RNE float->bf16
  unsigned u = __builtin_bit_cast(unsigned, f);
  u += 0x7fffu + ((u >> 16) & 1u);
  return (short)(u >> 16);
}

// relu(u+v) for a packed pair of bf16 (one dword each), round-half-up pack.
__device__ __forceinline__ unsigned hpair(unsigned ud, unsigned vd) {
  float ulo = __builtin_bit_cast(float, ud << 16);
  float uhi = __builtin_bit_cast(float, ud & 0xffff0000u);
  float vlo = __builtin_bit_cast(float, vd << 16);
  float vhi = __builtin_bit_cast(float, vd & 0xffff0000u);
  float slo = fmaxf(ulo + vlo, 0.f);
  float shi = fmaxf(uhi + vhi, 0.f);
  unsigned rlo = __builtin_bit_cast(unsigned, slo) + 0x8000u;
  unsigned rhi = __builtin_bit_cast(unsigned, shi) + 0x8000u;
  return (rhi & 0xffff0000u) | (rlo >> 16);
}

// ================= prep: one WG per slab (240), 256 threads =================
// Writes: W2L (blocks 0..31), UV[bt] = UL image (8192 shorts) + VL image
// (8192 shorts), all_is_obj[bt] (1024 floats).
__global__ __launch_bounds__(256) void orn_prep(
    const float* __restrict__ objs, const float* __restrict__ W1,
    const float* __restrict__ b1, const float* __restrict__ W2,
    short* __restrict__ W2L, short* __restrict__ UV, float* __restrict__ out) {
  __shared__ short ULs[32 * 32 * 8];   // [kb=o>>3][i][jj] bf16 of U'=U+b1 (16 KB)
  __shared__ short VLs[32 * 32 * 8];   // [kb][j][jj]                      (16 KB)
  float* PS = (float*)ULs;             // phase-1 scratch, dead before UL writes
  float* FC = PS + 256;

  const int tid = threadIdx.x;
  const int bt  = blockIdx.x;          // 0..239
  const int b   = bt / 15;
  const int tm  = bt - b * 15;         // t-1
  const float* O = objs + (size_t)(b * 16 + tm + 1) * (32 * 128);

  const int lane = tid & 63;
  const int w    = tid >> 6;
  const int l15  = lane & 15;
  const int quad = lane >> 4;
  const int n0   = w * 64;

  // ---- W2 -> bf16 A-frag, per-o-quarter contiguous (blocks 0..31 only) ----
  if (bt < 32) {
    int t = bt * 256 + tid;            // t == kb*256 + o
    int kb = t >> 8, o = t & 255;
    const float* p = W2 + (size_t)o * 256 + kb * 8;
    float4 x = *(const float4*)p;
    float4 y = *(const float4*)(p + 4);
    bf16x8 f;
    f[0] = f2bf(x.x); f[1] = f2bf(x.y); f[2] = f2bf(x.z); f[3] = f2bf(x.w);
    f[4] = f2bf(y.x); f[5] = f2bf(y.y); f[6] = f2bf(y.z); f[7] = f2bf(y.w);
    int idx = ((o >> 6) * 32 + kb) * 64 + (o & 63);
    *(bf16x8*)&W2L[(size_t)idx * 8] = f;
  }

  // ---------------- Phase 1: fp32 row sums -> all_is_obj ----------------
  {
    int i = tid >> 3, c = tid & 7;
    const float* p = O + i * 128 + c * 16;
    float s = 0.f;
#pragma unroll
    for (int e = 0; e < 4; e++) {
      float4 v = *(const float4*)(p + e * 4);
      s += v.x + v.y + v.z + v.w;
    }
    PS[tid] = s;
  }
  __syncthreads();
  if (tid < 32) {
    float s = 0.f;
#pragma unroll
    for (int c = 0; c < 8; c++) s += PS[tid * 8 + c];
    FC[tid] = fminf(fmaxf(s, 0.f), 1.f);
  }
  __syncthreads();
#pragma unroll
  for (int rep = 0; rep < 4; rep++) {
    int p = rep * 256 + tid;
    int i = p >> 5, j = p & 31;
    float v = FC[i] * FC[j] * (float)(tm + 1);
    out[E_ELEMS + (size_t)bt * 1024 + p] = fminf(fmaxf(v, 0.f), 1.f);
  }

  // ---------------- Phase 2: U'/V (32x256) via MFMA ----------------
  f32x4 accU[2][4], accV[2][4];
  {
    bf16x8 afr[2][4];                  // O as A: A[i=ms*16+l15][k=ks*32+quad*8+jj]
#pragma unroll
    for (int ms = 0; ms < 2; ms++)
#pragma unroll
      for (int ks = 0; ks < 4; ks++) {
        const float* p = O + (ms * 16 + l15) * 128 + ks * 32 + quad * 8;
        float4 x = *(const float4*)p;
        float4 y = *(const float4*)(p + 4);
        bf16x8 f;
        f[0] = f2bf(x.x); f[1] = f2bf(x.y); f[2] = f2bf(x.z); f[3] = f2bf(x.w);
        f[4] = f2bf(y.x); f[5] = f2bf(y.y); f[6] = f2bf(y.z); f[7] = f2bf(y.w);
        afr[ms][ks] = f;
      }
    const f32x4 zf = {0.f, 0.f, 0.f, 0.f};
#pragma unroll
    for (int ms = 0; ms < 2; ms++)
#pragma unroll
      for (int ns = 0; ns < 4; ns++) { accU[ms][ns] = zf; accV[ms][ns] = zf; }
#pragma unroll
    for (int ks = 0; ks < 4; ks++) {
#pragma unroll
      for (int ns = 0; ns < 4; ns++) {
        const float* pu = W1 + (size_t)(n0 + ns * 16 + l15) * 256 + ks * 32 + quad * 8;
        float4 xu = *(const float4*)pu;
        float4 yu = *(const float4*)(pu + 4);
        float4 xv = *(const float4*)(pu + 128);
        float4 yv = *(const float4*)(pu + 132);
        bf16x8 bu, bv;
        bu[0] = f2bf(xu.x); bu[1] = f2bf(xu.y); bu[2] = f2bf(xu.z); bu[3] = f2bf(xu.w);
        bu[4] = f2bf(yu.x); bu[5] = f2bf(yu.y); bu[6] = f2bf(yu.z); bu[7] = f2bf(yu.w);
        bv[0] = f2bf(xv.x); bv[1] = f2bf(xv.y); bv[2] = f2bf(xv.z); bv[3] = f2bf(xv.w);
        bv[4] = f2bf(yv.x); bv[5] = f2bf(yv.y); bv[6] = f2bf(yv.z); bv[7] = f2bf(yv.w);
#pragma unroll
        for (int ms = 0; ms < 2; ms++) {
          accU[ms][ns] = MFMA16(afr[ms][ks], bu, accU[ms][ns]);
          accV[ms][ns] = MFMA16(afr[ms][ks], bv, accV[ms][ns]);
        }
      }
    }
  }
  __syncthreads();                     // FC consumers done -> overwrite ULs

  // D: col=l15 -> o, row=quad*4+r -> i. Fold b1 into U'.
#pragma unroll
  for (int ms = 0; ms < 2; ms++)
#pragma unroll
    for (int ns = 0; ns < 4; ns++) {
      int o  = n0 + ns * 16 + l15;
      float bb = b1[o];
      int kb = o >> 3, jj = o & 7;
#pragma unroll
      for (int r = 0; r < 4; r++) {
        int i = ms * 16 + quad * 4 + r;
        ULs[(kb * 32 + i) * 8 + jj] = f2bf(accU[ms][ns][r] + bb);
        VLs[(kb * 32 + i) * 8 + jj] = f2bf(accV[ms][ns][r]);
      }
    }
  __syncthreads();

  // ---- linear copy-out of the fragment images (fully coalesced) ----
  short* UVb = UV + (size_t)bt * 16384;
#pragma unroll
  for (int it = 0; it < 4; it++) {
    int idx = it * 256 + tid;
    *(bf16x8*)&UVb[(size_t)idx * 8] = *(const bf16x8*)&ULs[idx * 8];
    *(bf16x8*)&UVb[8192 + (size_t)idx * 8] = *(const bf16x8*)&VLs[idx * 8];
  }
}

// ================= main: 960 WGs = 240 slabs x 4 o-quarters ==================
__global__ __launch_bounds__(256, 2) void orn_main(
    const float* __restrict__ b2, const short* __restrict__ W2L,
    const short* __restrict__ UV, float* __restrict__ out) {
  __shared__ short SH[32768];          // AW [0,16384) | UL [16384,24576) | VL [24576,32768)
  short* AW  = SH;                     // [kb][m=o-64q][jj] W2 A-frags (32 KB)
  short* ULs = SH + 16384;
  short* VLs = SH + 24576;

  const int tid = threadIdx.x;
  const int bid = blockIdx.x;
  // swizzle: same-slab WGs (4 q's) differ by 8 in bid -> same XCD
  const int bt  = (bid & 7) | ((bid >> 5) << 3);   // 0..239
  const int q   = (bid >> 3) & 3;                  // o-quarter

  const int lane = tid & 63;
  const int w    = tid >> 6;
  const int l15  = lane & 15;
  const int quad = lane >> 4;

  // ---- 64 KB copy-in: W2 slice + U/V images (linear, coalesced) ----
  {
    const short* W2q = W2L + (size_t)q * 16384;
    const short* UVb = UV + (size_t)bt * 16384;
#pragma unroll
    for (int it = 0; it < 8; it++) {
      int idx = it * 256 + tid;
      *(bf16x8*)&AW[idx * 8] = *(const bf16x8*)&W2q[(size_t)idx * 8];
    }
#pragma unroll
    for (int it = 0; it < 8; it++) {
      int idx = it * 256 + tid;
      *(bf16x8*)&ULs[idx * 8] = *(const bf16x8*)&UVb[(size_t)idx * 8];
    }
  }

  f32x4 b2v[4];                        // b2[o] for o = 64q + ms*16 + quad*4 + r
#pragma unroll
  for (int ms = 0; ms < 4; ms++)
    b2v[ms] = *(const f32x4*)&b2[q * 64 + ms * 16 + quad * 4];

  __syncthreads();                     // ONLY barrier

  const int PB = w * 256;              // wave's pair base within slab
  const f32x4 zf = {0.f, 0.f, 0.f, 0.f};

#pragma unroll 1
  for (int c = 0; c < 4; c++) {        // 4 chunks of 64 pairs; barrier-free
    f32x4 acc[4][4];                   // [ms: o-16tile][ns: p-16tile]
#pragma unroll
    for (int ms = 0; ms < 4; ms++)
#pragma unroll
      for (int ns = 0; ns < 4; ns++) acc[ms][ns] = zf;

#pragma unroll
    for (int ks = 0; ks < 8; ks++) {
      const int kb = ks * 4 + quad;
      bf16x8 aw4[4];                   // W2 A-frags from LDS (WG-shared)
#pragma unroll
      for (int ms = 0; ms < 4; ms++)
        aw4[ms] = *(const bf16x8*)&AW[(kb * 64 + ms * 16 + l15) * 8];
#pragma unroll
      for (int ns = 0; ns < 4; ns++) {
        // B[k=quad*8+jj][n=p]: h row p = PB + c*64 + ns*16 + l15
        int pl = ns * 16 + l15;
        int i  = 8 * w + 2 * c + (pl >> 5);
        int j  = pl & 31;
        uint4 ud = *(const uint4*)&ULs[(kb * 32 + i) * 8];  // broadcast in quad
        uint4 vd = *(const uint4*)&VLs[(kb * 32 + j) * 8];  // 256B contiguous
        uint4 hd;
        hd.x = hpair(ud.x, vd.x);
        hd.y = hpair(ud.y, vd.y);
        hd.z = hpair(ud.z, vd.z);
        hd.w = hpair(ud.w, vd.w);
        bf16x8 hh = __builtin_bit_cast(bf16x8, hd);
#pragma unroll
        for (int ms = 0; ms < 4; ms++)
          acc[ms][ns] = MFMA16(aw4[ms], hh, acc[ms][ns]);
      }
    }

    // epilogue: lane holds e[p = PB+c*64+ns*16+l15][o = 64q+ms*16+quad*4+r].
    // ns OUTER so ms-stores (64B halves of 128B lines) are adjacent.
    size_t rowbase = (size_t)bt * 1024 + PB + c * 64;
#pragma unroll
    for (int ns = 0; ns < 4; ns++) {
      size_t row = rowbase + ns * 16 + l15;
      float* rp = &out[row * 256 + q * 64 + quad * 4];
#pragma unroll
      for (int ms = 0; ms < 4; ms++) {
        f32x4 vs;
        vs.x = fmaxf(acc[ms][ns][0] + b2v[ms].x, 0.f);
        vs.y = fmaxf(acc[ms][ns][1] + b2v[ms].y, 0.f);
        vs.z = fmaxf(acc[ms][ns][2] + b2v[ms].z, 0.f);
        vs.w = fmaxf(acc[ms][ns][3] + b2v[ms].w, 0.f);
        *(f32x4*)(rp + ms * 16) = vs;
      }
    }
  }
}

extern "C" void kernel_launch(void* const* d_in, const int* in_sizes, int n_in,
                              void* d_out, int out_size, void* d_ws, size_t ws_size,
                              hipStream_t stream) {
  const float* objs = (const float*)d_in[0];
  const float* W1   = (const float*)d_in[1];
  const float* b1   = (const float*)d_in[2];
  const float* W2   = (const float*)d_in[3];
  const float* b2   = (const float*)d_in[4];
  float* out = (float*)d_out;
  short* W2L = (short*)d_ws;                 // 128 KB bf16 A-frag W2 (4 quarters)
  short* UV  = W2L + 65536;                  // 240 x 32 KB U'/V fragment images

  orn_prep<<<240, 256, 0, stream>>>(objs, W1, b1, W2, W2L, UV, out);
  orn_main<<<960, 256, 0, stream>>>(b2, W2L, UV, out);
}